// Round 1
// 251.280 us; speedup vs baseline: 1.0127x; 1.0127x over previous
//
#include <hip/hip_runtime.h>

// Embedding gather: out[token, :] = kernel[idx[token], :]  (all f32)
// TOKENS = 262144, EMBED = 256 (1 KiB/row), VOCAB = 256 (table 256 KiB,
// L2-resident). Output = 256 MiB of pure HBM writes -> ~41 us floor at the
// fill-demonstrated 6.6 TB/s.
//
// R5 (prev): persistent waves, 64 rows/wave, unroll 4. Rocprof shows the
// kernel itself is <162 us (absent from top-5; harness 254 us includes a
// ~162 us 1 GiB poison fill) -> kernel ~92 us, 2.2x off the write roofline.
// Theory: unroll-4 with register reuse each group = stall-and-go (wait full
// L2 load latency, then wait store completion before regs can be reused);
// effective MLP ~4.
//
// R6: software-pipelined double buffer. Two reg buffers of G=8 rows; steady
// state issues the next 8 loads before storing the previous 8, so >=8 vmem
// ops are in flight continuously and the wave never drains. Fully unrolled:
// all readlane lane operands and buffer indices are compile-time constants
// (no scratch). 32 rows/wave, 8192 waves / 2048 blocks.

#define EMBED 256
#define CHUNKS_PER_ROW (EMBED / 4)      // 64 x 16B chunks per 1 KiB row
#define ROWS_PER_WAVE 32
#define WAVES_PER_BLOCK 4
#define G 8                              // pipeline depth (rows per buffer)

typedef unsigned int u32x4 __attribute__((ext_vector_type(4)));

__global__ __launch_bounds__(256) void embedding_gather_kernel(
    const int* __restrict__ indices,          // [TOKENS] int32
    const u32x4* __restrict__ table,          // [VOCAB*EMBED] f32 as 16B chunks
    u32x4* __restrict__ out,                  // [TOKENS*EMBED] f32 as 16B chunks
    int tokens)
{
    const int lane    = threadIdx.x & 63;
    const int wave_id = blockIdx.x * WAVES_PER_BLOCK + (threadIdx.x >> 6);
    const long row_base = (long)wave_id * ROWS_PER_WAVE;
    if (row_base >= tokens) return;

    // One coalesced load: lane l holds the index for row (row_base + l).
    int my_idx = 0;
    if (row_base + lane < tokens) my_idx = indices[row_base + lane];

    const u32x4* __restrict__ tb  = table + lane;                       // + lane*16B
    u32x4* __restrict__       dst = out + (size_t)row_base * CHUNKS_PER_ROW + lane;

    const long rem  = tokens - row_base;
    const int  rows = rem < ROWS_PER_WAVE ? (int)rem : ROWS_PER_WAVE;

    if (rows == ROWS_PER_WAVE) {
        u32x4 bufA[G], bufB[G];

        // Prologue: rows 0..G-1 in flight.
        #pragma unroll
        for (int g = 0; g < G; ++g) {
            const int idx = __builtin_amdgcn_readlane(my_idx, g);
            bufA[g] = tb[(size_t)idx * CHUNKS_PER_ROW];
        }

        // Steady state: 2*G rows per iteration, fully unrolled (trip = 2).
        #pragma unroll
        for (int i = 0; i < ROWS_PER_WAVE; i += 2 * G) {
            // Issue next G loads before storing the previous G.
            #pragma unroll
            for (int g = 0; g < G; ++g) {
                const int idx = __builtin_amdgcn_readlane(my_idx, i + G + g);
                bufB[g] = tb[(size_t)idx * CHUNKS_PER_ROW];
            }
            #pragma unroll
            for (int g = 0; g < G; ++g)
                dst[(size_t)(i + g) * CHUNKS_PER_ROW] = bufA[g];

            if (i + 2 * G < ROWS_PER_WAVE) {   // compile-time after unroll
                #pragma unroll
                for (int g = 0; g < G; ++g) {
                    const int idx = __builtin_amdgcn_readlane(my_idx, i + 2 * G + g);
                    bufA[g] = tb[(size_t)idx * CHUNKS_PER_ROW];
                }
            }
            #pragma unroll
            for (int g = 0; g < G; ++g)
                dst[(size_t)(i + G + g) * CHUNKS_PER_ROW] = bufB[g];
        }
    } else {
        // Partial tail wave (not hit at 262144 tokens, kept for safety).
        for (int i = 0; i < rows; ++i) {
            const int idx = __builtin_amdgcn_readlane(my_idx, i);
            dst[(size_t)i * CHUNKS_PER_ROW] = tb[(size_t)idx * CHUNKS_PER_ROW];
        }
    }
}

extern "C" void kernel_launch(void* const* d_in, const int* in_sizes, int n_in,
                              void* d_out, int out_size, void* d_ws, size_t ws_size,
                              hipStream_t stream) {
    const int*   indices = (const int*)d_in[0];    // [262144] int32
    const u32x4* table   = (const u32x4*)d_in[1];  // [256*256] f32 as 16B chunks
    u32x4*       out     = (u32x4*)d_out;          // [262144*256] f32 as 16B chunks

    const int tokens = in_sizes[0];                                       // 262144
    const int waves  = (tokens + ROWS_PER_WAVE - 1) / ROWS_PER_WAVE;      // 8192
    const int blocks = (waves + WAVES_PER_BLOCK - 1) / WAVES_PER_BLOCK;   // 2048

    embedding_gather_kernel<<<blocks, 256, 0, stream>>>(indices, table, out, tokens);
}